// Round 5
// baseline (297.470 us; speedup 1.0000x reference)
//
#include <hip/hip_runtime.h>
#include <stdint.h>

// SelfAttention: B=4 S=4096 d_model=1024 d_out=64, fp32 in/out.
// prep: W->bf16^T (swizzle-ready), fold log2e/8 into Wq,bq.
// proj: W (128KB bf16, full K) resident in LDS (staged once); X streamed per-lane
//       directly into A-fragments (no LDS, no main-loop barriers). bf16 MFMA.
// attn: flash, 512 blocks XCD-mapped, global_load_lds K/V dbuf, setprio on MFMA.

typedef __attribute__((ext_vector_type(8))) short bf16x8;
typedef __attribute__((ext_vector_type(4))) float f32x4;

#define LOG2E_OVER8 0.1803368801111204f

#define GLOAD16(gptr, lptr)                                                            \
  __builtin_amdgcn_global_load_lds((const __attribute__((address_space(1))) uint32_t*)(gptr), \
                                   (__attribute__((address_space(3))) uint32_t*)(lptr), 16, 0, 0)

__device__ __forceinline__ unsigned short f2bf(float f) {
  union { float f; uint32_t u; } v; v.f = f;
  return (unsigned short)((v.u + 0x7FFFu + ((v.u >> 16) & 1u)) >> 16);
}
__device__ __forceinline__ uint32_t f2bf2(float a, float b) {
  return (uint32_t)f2bf(a) | ((uint32_t)f2bf(b) << 16);
}
__device__ __forceinline__ unsigned short f2bf_fast(float f) {  // round-half-up (P values only)
  union { float f; uint32_t u; } v; v.f = f;
  return (unsigned short)((v.u + 0x8000u) >> 16);
}

// ---------------- prep: W (1024x64 f32) -> wt[3][64][1024] bf16 (transposed), bias f32 ----
__global__ void prep_kernel(const float* __restrict__ Wq, const float* __restrict__ bq,
                            const float* __restrict__ Wk, const float* __restrict__ bk,
                            const float* __restrict__ Wv, const float* __restrict__ bv,
                            unsigned short* __restrict__ wt, float* __restrict__ bias) {
  int idx = blockIdx.x * 256 + threadIdx.x;      // 0..196607
  int p = idx >> 16;
  int rem = idx & 65535;                          // = k*64 + col
  int k = rem >> 6, col = rem & 63;
  const float* W = p == 0 ? Wq : (p == 1 ? Wk : Wv);
  float scale = (p == 0) ? LOG2E_OVER8 : 1.0f;
  wt[(p << 16) + col * 1024 + k] = f2bf(W[rem] * scale);
  if (idx < 192) {
    int pp = idx >> 6, cc = idx & 63;
    const float* bsrc = pp == 0 ? bq : (pp == 1 ? bk : bv);
    bias[idx] = bsrc[cc] * ((pp == 0) ? LOG2E_OVER8 : 1.0f);
  }
}

// ---------------- proj: X[16384,1024] @ W[1024,64] + b -> bf16 --------------------------
// BM=128, 8 waves x 16 rows. Whole W^T (64x1024 bf16 = 128 KB) staged to LDS once
// (XOR-swizzled, via global_load_lds). X read per-lane straight into A-fragments:
// lane(c,G) owns row row0+wv*16+c, k-slice G*8..+8 per half-step. No main-loop barriers.
__global__ __launch_bounds__(512)
void proj_kernel(const float* __restrict__ Xq, const float* __restrict__ Xk,
                 const float* __restrict__ Xv,
                 const unsigned short* __restrict__ wt, const float* __restrict__ bias,
                 unsigned short* __restrict__ qo, unsigned short* __restrict__ ko,
                 unsigned short* __restrict__ vo) {
  __shared__ unsigned short Wlds[16][64][64];    // [k-chunk][col][k-in-chunk] = 128 KB
  const int p = blockIdx.y;
  const float* X = p == 0 ? Xq : (p == 1 ? Xk : Xv);
  const int row0 = blockIdx.x * 128;
  const int tid = threadIdx.x;
  const int lane = tid & 63, wv = tid >> 6, cc = lane & 15, G = lane >> 4;

  { // stage full W^T for this p: wave wv stages chunks wv*2, wv*2+1 (8 x 1KB each)
    char* wl = (char*)&Wlds[0][0][0];
#pragma unroll
    for (int c2 = 0; c2 < 2; c2++) {
      int ch = wv * 2 + c2;
#pragma unroll
      for (int i = 0; i < 8; i++) {
        int r = i * 8 + (lane >> 3);
        int s = lane & 7;
        const unsigned short* src = wt + (p << 16) + r * 1024 + ch * 64 + ((s ^ (r & 7)) << 3);
        GLOAD16(src, wl + ch * 8192 + i * 1024);
      }
    }
  }
  __syncthreads();   // only barrier in the kernel

  const float* xrow = X + (size_t)(row0 + wv * 16 + cc) * 1024;
  const char* wl = (const char*)&Wlds[0][0][0];

  f32x4 acc[4] = {};
  float4 xf[3][4];   // rotating prefetch buffers (statically indexed via full unroll)

#define LOADX(jj)                                                              \
  {                                                                            \
    const float4* s_ = (const float4*)(xrow + (jj) * 64);                      \
    xf[(jj) % 3][0] = s_[G * 2];       xf[(jj) % 3][1] = s_[G * 2 + 1];        \
    xf[(jj) % 3][2] = s_[8 + G * 2];   xf[(jj) % 3][3] = s_[8 + G * 2 + 1];    \
  }

  LOADX(0);
  LOADX(1);
#pragma unroll
  for (int j = 0; j < 16; j++) {
    if (j < 14) LOADX(j + 2);
#pragma unroll
    for (int k2 = 0; k2 < 2; k2++) {
      float4 p0 = xf[j % 3][k2 * 2];
      float4 p1 = xf[j % 3][k2 * 2 + 1];
      union { uint32_t u[4]; bf16x8 v; } cv;
      cv.u[0] = f2bf2(p0.x, p0.y); cv.u[1] = f2bf2(p0.z, p0.w);
      cv.u[2] = f2bf2(p1.x, p1.y); cv.u[3] = f2bf2(p1.z, p1.w);
      bf16x8 a = cv.v;
#pragma unroll
      for (int n = 0; n < 4; n++) {
        bf16x8 bw = *(const bf16x8*)(wl + j * 8192 + (16 * n + cc) * 128 +
                                     (((k2 * 4 + G) ^ (cc & 7)) << 4));
        acc[n] = __builtin_amdgcn_mfma_f32_16x16x32_bf16(a, bw, acc[n], 0, 0, 0);
      }
    }
  }
#undef LOADX

  float bcol[4];
#pragma unroll
  for (int n = 0; n < 4; n++) bcol[n] = bias[p * 64 + 16 * n + cc];
  if (p < 2) {
    unsigned short* out = (p == 0) ? qo : ko;
#pragma unroll
    for (int n = 0; n < 4; n++)
#pragma unroll
      for (int r = 0; r < 4; r++) {
        int row = row0 + wv * 16 + G * 4 + r;
        out[(size_t)row * 64 + 16 * n + cc] = f2bf(acc[n][r] + bcol[n]);
      }
  } else {
#pragma unroll
    for (int n = 0; n < 4; n++)
#pragma unroll
      for (int r = 0; r < 4; r++) {
        int row = row0 + wv * 16 + G * 4 + r;   // global s index
        int bb = row >> 12, sl = row & 4095;
        int e = 16 * n + cc;
        vo[((size_t)(bb * 64 + e) << 12) + sl] = f2bf(acc[n][r] + bcol[n]);
      }
  }
}

// ---------------- flash attention ------------------------------------------------------
// 512 blocks (XCD-remapped: each XCD sees one batch), 4 waves: ws_=q-strip(16 rows),
// g=KV half (2048 keys). K/V staged via global_load_lds (XOR-swizzled source),
// double-buffered, one barrier per KV tile. setprio(1) around MFMA clusters (T5).
__global__ __launch_bounds__(256)
void attn_kernel(const unsigned short* __restrict__ q_ws, const unsigned short* __restrict__ k_ws,
                 const unsigned short* __restrict__ vt_ws, float* __restrict__ out) {
  __shared__ unsigned short Ks[2][2][64][64];  // [buf][group][key][d] 32 KB
  __shared__ unsigned short Vs[2][2][64][64];  // [buf][group][d][key] 32 KB
  __shared__ uint32_t Pl[4][16][36];           // per-wave P tile (padded)
  __shared__ float msh[2][16], lsh[2][16];
  const int bid = blockIdx.x;
  const int b = (bid & 7) >> 1;                       // batch -> XCD pair
  const int xt = ((bid >> 3) << 1) | (bid & 1);       // q-tile 0..127
  const int tid = threadIdx.x;
  const int lane = tid & 63, wv = tid >> 6, c = lane & 15, G = lane >> 4;
  const int ws_ = wv & 1, g = wv >> 1;
  const int qrow = xt * 32 + ws_ * 16;
  const int wvoff = wv * 1024;

  // staging coords: call h covers rows h*32..+31; chunk = h*256 + tid
  const int srow = tid >> 3;                          // 0..31
  const int scol = ((tid & 7) ^ (srow & 7)) * 8;      // pre-swizzled elem offset

  bf16x8 aq[2];
#pragma unroll
  for (int k2 = 0; k2 < 2; k2++)
    aq[k2] = *(const bf16x8*)(q_ws + ((size_t)(b * 4096 + qrow + c) << 6) + k2 * 32 + G * 8);

  f32x4 o[4] = {};
  float mr[4] = {-1e30f, -1e30f, -1e30f, -1e30f};
  float lp[4] = {};

  auto STAGE = [&](int bufi, int t) {
#pragma unroll
    for (int gb = 0; gb < 2; gb++) {
      int kv0 = gb * 2048 + t * 64;
      char* kb = (char*)&Ks[bufi][gb][0][0];
      char* vb = (char*)&Vs[bufi][gb][0][0];
#pragma unroll
      for (int h = 0; h < 2; h++) {
        const unsigned short* ksrc = k_ws + ((size_t)(b * 4096 + kv0 + h * 32 + srow) << 6) + scol;
        GLOAD16(ksrc, kb + h * 4096 + wvoff);
        const unsigned short* vsrc = vt_ws + ((size_t)(b * 64 + h * 32 + srow) << 12) + kv0 + scol;
        GLOAD16(vsrc, vb + h * 4096 + wvoff);
      }
    }
  };

  STAGE(0, 0);
  __syncthreads();
  int buf = 0;
  for (int t = 0; t < 32; t++) {
    if (t < 31) STAGE(buf ^ 1, t + 1);
    const char* kb = (const char*)&Ks[buf][g][0][0];
    const char* vb = (const char*)&Vs[buf][g][0][0];

    // scores = q.k (exp2 domain, pre-scaled)
    f32x4 sc[4] = {};
    __builtin_amdgcn_s_setprio(1);
#pragma unroll
    for (int k2 = 0; k2 < 2; k2++)
#pragma unroll
      for (int f = 0; f < 4; f++) {
        bf16x8 bk = *(const bf16x8*)(kb + (16 * f + c) * 128 + (((k2 * 4 + G) ^ (c & 7)) * 16));
        sc[f] = __builtin_amdgcn_mfma_f32_16x16x32_bf16(aq[k2], bk, sc[f], 0, 0, 0);
      }
    __builtin_amdgcn_s_setprio(0);

    // online softmax (row r lives in 16 lanes sharing G)
    float mn[4];
#pragma unroll
    for (int r = 0; r < 4; r++)
      mn[r] = fmaxf(fmaxf(sc[0][r], sc[1][r]), fmaxf(sc[2][r], sc[3][r]));
#pragma unroll
    for (int msk = 1; msk <= 8; msk <<= 1)
#pragma unroll
      for (int r = 0; r < 4; r++)
        mn[r] = fmaxf(mn[r], __shfl_xor(mn[r], msk));

    float pv[4][4];
#pragma unroll
    for (int r = 0; r < 4; r++) {
      float M = fmaxf(mr[r], mn[r]);
      float al = __builtin_amdgcn_exp2f(mr[r] - M);
      mr[r] = M;
      lp[r] *= al;
#pragma unroll
      for (int df = 0; df < 4; df++) o[df][r] *= al;
#pragma unroll
      for (int f = 0; f < 4; f++) pv[f][r] = __builtin_amdgcn_exp2f(sc[f][r] - M);
      lp[r] += (pv[0][r] + pv[1][r]) + (pv[2][r] + pv[3][r]);
    }

    // P -> bf16 via per-wave LDS tile (D-frag -> A-frag relayout)
    unsigned short* plw = (unsigned short*)&Pl[wv][0][0];
#pragma unroll
    for (int f = 0; f < 4; f++)
#pragma unroll
      for (int r = 0; r < 4; r++)
        plw[(4 * G + r) * 72 + 16 * f + c] = f2bf_fast(pv[f][r]);

    bf16x8 pa[2];
    pa[0] = *(const bf16x8*)((const char*)&Pl[wv][0][0] + c * 144 + G * 16);
    pa[1] = *(const bf16x8*)((const char*)&Pl[wv][0][0] + c * 144 + 64 + G * 16);
    __builtin_amdgcn_s_setprio(1);
#pragma unroll
    for (int k2 = 0; k2 < 2; k2++)
#pragma unroll
      for (int df = 0; df < 4; df++) {
        bf16x8 bvv = *(const bf16x8*)(vb + (16 * df + c) * 128 + (((k2 * 4 + G) ^ (c & 7)) * 16));
        o[df] = __builtin_amdgcn_mfma_f32_16x16x32_bf16(pa[k2], bvv, o[df], 0, 0, 0);
      }
    __builtin_amdgcn_s_setprio(0);
    __syncthreads();
    buf ^= 1;
  }

  // finish l reduction across the 16-lane row group
#pragma unroll
  for (int msk = 1; msk <= 8; msk <<= 1)
#pragma unroll
    for (int r = 0; r < 4; r++) lp[r] += __shfl_xor(lp[r], msk);

  // merge the two KV-half partials (reuse Ks as f32 scratch)
  float* Osh = (float*)&Ks[0][0][0][0];   // [2][16][65]
  if (g == 1) {
#pragma unroll
    for (int df = 0; df < 4; df++)
#pragma unroll
      for (int r = 0; r < 4; r++)
        Osh[(ws_ * 16 + 4 * G + r) * 65 + 16 * df + c] = o[df][r];
    if (c == 0) {
#pragma unroll
      for (int r = 0; r < 4; r++) {
        msh[ws_][4 * G + r] = mr[r];
        lsh[ws_][4 * G + r] = lp[r];
      }
    }
  }
  __syncthreads();
  if (g == 0) {
#pragma unroll
    for (int r = 0; r < 4; r++) {
      int rowi = 4 * G + r;
      float m1 = msh[ws_][rowi], l1 = lsh[ws_][rowi];
      float M = fmaxf(mr[r], m1);
      float a0 = __builtin_amdgcn_exp2f(mr[r] - M);
      float a1 = __builtin_amdgcn_exp2f(m1 - M);
      float inv = 1.0f / (a0 * lp[r] + a1 * l1);
#pragma unroll
      for (int df = 0; df < 4; df++) {
        float val = (a0 * o[df][r] + a1 * Osh[(ws_ * 16 + rowi) * 65 + 16 * df + c]) * inv;
        out[((size_t)(b * 4096 + qrow + rowi) << 6) + 16 * df + c] = val;
      }
    }
  }
}

// ---------------- launch ---------------------------------------------------------------
extern "C" void kernel_launch(void* const* d_in, const int* in_sizes, int n_in,
                              void* d_out, int out_size, void* d_ws, size_t ws_size,
                              hipStream_t stream) {
  const float* query = (const float*)d_in[0];
  const float* key   = (const float*)d_in[1];
  const float* value = (const float*)d_in[2];
  const float* Wq = (const float*)d_in[3];
  const float* bq = (const float*)d_in[4];
  const float* Wk = (const float*)d_in[5];
  const float* bk = (const float*)d_in[6];
  const float* Wv = (const float*)d_in[7];
  const float* bv = (const float*)d_in[8];

  char* ws = (char*)d_ws;
  unsigned short* q_ws  = (unsigned short*)(ws);                    // [4][4096][64] bf16, pre-scaled
  unsigned short* k_ws  = (unsigned short*)(ws + (2u << 20));       // [4][4096][64] bf16
  unsigned short* vt_ws = (unsigned short*)(ws + (4u << 20));       // [4][64][4096] bf16 (transposed)
  unsigned short* wt_ws = (unsigned short*)(ws + (6u << 20));       // [3][64][1024] bf16
  float* bias_ws        = (float*)(ws + (6u << 20) + 393216);       // [3][64] f32

  prep_kernel<<<768, 256, 0, stream>>>(Wq, bq, Wk, bk, Wv, bv, wt_ws, bias_ws);
  proj_kernel<<<dim3(128, 3), 512, 0, stream>>>(query, key, value, wt_ws, bias_ws,
                                                q_ws, k_ws, vt_ws);
  attn_kernel<<<512, 256, 0, stream>>>(q_ws, k_ws, vt_ws, (float*)d_out);
}